// Round 1
// 1438.667 us; speedup vs baseline: 1.0450x; 1.0450x over previous
//
#include <hip/hip_runtime.h>

#define NTOK   8192
#define DMODEL 1024
#define NATOM  16384

typedef _Float16 half8  __attribute__((ext_vector_type(8)));
typedef _Float16 half4_t __attribute__((ext_vector_type(4)));
typedef float    f32x4  __attribute__((ext_vector_type(4)));

// async global->LDS, 16B per lane; LDS dest is wave-uniform base + lane*16
#define GLOAD_LDS16(gsrc, ldst) \
  __builtin_amdgcn_global_load_lds((const __attribute__((address_space(1))) unsigned int*)(gsrc), \
                                   (__attribute__((address_space(3))) unsigned int*)(ldst), 16, 0, 0)

// ---------------- prep: fp32 -> fp16 (x only) ----------------
__global__ void cvt_f32_f16(const float* __restrict__ in, _Float16* __restrict__ out, int n4) {
  int i = blockIdx.x * 256 + threadIdx.x;
  if (i >= n4) return;
  float4 v = ((const float4*)in)[i];
  half4_t h;
  h[0] = (_Float16)v.x; h[1] = (_Float16)v.y; h[2] = (_Float16)v.z; h[3] = (_Float16)v.w;
  ((half4_t*)out)[i] = h;
}

// ---------------- prep: dict f32 -> Dh [16384,1024] f16 AND dT [1024,16384] f16 ----------------
__global__ void transpose_dict(const float* __restrict__ dict,
                               _Float16* __restrict__ Dh, _Float16* __restrict__ dT) {
  __shared__ _Float16 tile[64][68];
  int a0 = blockIdx.x * 64;   // atom tile
  int d0 = blockIdx.y * 64;   // dim tile
  int tid = threadIdx.x;
  int c = tid & 63;
  int r0 = tid >> 6;
  #pragma unroll
  for (int i = 0; i < 16; i++) {
    int r = r0 + i * 4;
    _Float16 h = (_Float16)dict[(size_t)(a0 + r) * DMODEL + d0 + c];
    tile[r][c] = h;
    Dh[(size_t)(a0 + r) * DMODEL + d0 + c] = h;
  }
  __syncthreads();
  #pragma unroll
  for (int i = 0; i < 16; i++) {
    int rd = r0 + i * 4;
    dT[(size_t)(d0 + rd) * NATOM + a0 + c] = tile[c][rd];
  }
}

__global__ void zero_lsum(float* __restrict__ lsum) {
  lsum[blockIdx.x * 256 + threadIdx.x] = 0.0f;
}

// staging helper: 128 rows x 32 k, XOR k-chunk swizzle on the global source side.
// Per wave: exactly 4 global_load_lds instructions (vmcnt += 4 per call).
__device__ __forceinline__ void stage_ab(const _Float16* __restrict__ A,
                                         const _Float16* __restrict__ B,
                                         _Float16* As, _Float16* Bs,
                                         size_t arow0, size_t brow0, size_t ldk,
                                         int k0, int tid) {
  #pragma unroll
  for (int i = 0; i < 2; i++) {
    int L = tid + i * 256;               // 0..511 = 128 rows x 4 chunks
    int r = L >> 2, pc = L & 3;
    int c = pc ^ ((r >> 1) & 3);
    GLOAD_LDS16(A + (arow0 + r) * ldk + k0 + c * 8, As + (size_t)L * 8);
    GLOAD_LDS16(B + (brow0 + r) * ldk + k0 + c * 8, Bs + (size_t)L * 8);
  }
}

// ---------------- kernel 1: E = mask ? exp(x @ dict^T) : 0, + row-tile sum/max ----------------
// 128x128 tile, BK=32, QUAD-buffered staging (4 x 16KB = 64KB LDS), counted vmcnt:
// tile t lives in buf[t&3]; phase t stages tile t+3 (3-phase prefetch lead, 12 loads/wave
// in flight); waits are vmcnt(8) in steady state — the vmcnt(0) drain of __syncthreads()
// never appears in the main loop. One raw s_barrier per phase.
__launch_bounds__(256, 2)
__global__ void score_kernel(const _Float16* __restrict__ Xh,
                             const _Float16* __restrict__ Dh,
                             const int* __restrict__ mask,
                             _Float16* __restrict__ E,
                             float* __restrict__ lsum,
                             _Float16* __restrict__ Tmax) {   // [128 tiles][8192 tokens]
  __shared__ _Float16 lds[32768];          // 4 bufs x (As 4096 + Bs 4096); epilogue reuses 128x136
  const int tid  = threadIdx.x;
  const int lane = tid & 63;
  const int wave = tid >> 6;
  const int wm = wave >> 1, wn = wave & 1;
  // XCD-aware swizzle: grid 8192 flat; each XCD gets 1024 consecutive tiles (8 token rows).
  const int swz = (blockIdx.x & 7) * 1024 + (blockIdx.x >> 3);
  const int nt = swz & 127;                // atom tile 0..127
  const int n0 = nt * 128;
  const int m0 = (swz >> 7) * 128;         // token tile

  const int frow = lane & 15;
  const int fkc  = lane >> 4;

  f32x4 acc[4][4] = {};

  // prologue: stage tiles 0,1,2 -> 12 loads/wave in flight
  stage_ab(Xh, Dh, lds,         lds + 4096,  m0, n0, DMODEL, 0,  tid);
  stage_ab(Xh, Dh, lds + 8192,  lds + 12288, m0, n0, DMODEL, 32, tid);
  stage_ab(Xh, Dh, lds + 16384, lds + 20480, m0, n0, DMODEL, 64, tid);

  for (int t = 0; t < 32; ++t) {
    // tile t resident once <= (tiles after t)*4 loads remain outstanding
    if (t < 30)       asm volatile("s_waitcnt vmcnt(8)" ::: "memory");
    else if (t == 30) asm volatile("s_waitcnt vmcnt(4)" ::: "memory");
    else              asm volatile("s_waitcnt vmcnt(0)" ::: "memory");
    __builtin_amdgcn_s_barrier();
    __builtin_amdgcn_sched_barrier(0);     // nothing hoists above the barrier
    const _Float16* As = lds + (t & 3) * 8192;
    const _Float16* Bs = As + 4096;
    half8 af[4], bf[4];
    #pragma unroll
    for (int i = 0; i < 4; i++) {
      int ar = wm * 64 + i * 16 + frow;
      int br = wn * 64 + i * 16 + frow;
      af[i] = *(const half8*)&As[ar * 32 + ((fkc ^ ((ar >> 1) & 3)) << 3)];
      bf[i] = *(const half8*)&Bs[br * 32 + ((fkc ^ ((br >> 1) & 3)) << 3)];
    }
    if (t + 3 < 32) {
      int b = (t + 3) & 3;                 // == (t-1)&3: buffer consumed last phase, barrier-safe
      stage_ab(Xh, Dh, lds + b * 8192, lds + b * 8192 + 4096, m0, n0, DMODEL, (t + 3) * 32, tid);
    }
    __builtin_amdgcn_s_setprio(1);
    #pragma unroll
    for (int i = 0; i < 4; i++)
      #pragma unroll
      for (int j = 0; j < 4; j++)
        acc[i][j] = __builtin_amdgcn_mfma_f32_16x16x32_f16(af[i], bf[j], acc[i][j], 0, 0, 0);
    __builtin_amdgcn_s_setprio(0);
    __builtin_amdgcn_sched_barrier(0);     // pin reads+lgkm+MFMA inside the phase
  }

  __syncthreads();
  // epilogue: C/D layout col=lane&15, row=(lane>>4)*4+reg. mask+exp -> LDS (stride 136) -> stores.
  const int cr = (lane >> 4) * 4;
  const int cc = lane & 15;
  #pragma unroll
  for (int i = 0; i < 4; i++) {
    #pragma unroll
    for (int j = 0; j < 4; j++) {
      #pragma unroll
      for (int r = 0; r < 4; r++) {
        int lr = wm * 64 + i * 16 + cr + r;
        int lc = wn * 64 + j * 16 + cc;
        int mk = mask[(size_t)(m0 + lr) * NATOM + (n0 + lc)];
        float e = mk ? __expf(acc[i][j][r]) : 0.0f;   // scores bounded |s|<=11: no max-subtract
        lds[lr * 136 + lc] = (_Float16)e;
      }
    }
  }
  __syncthreads();
  // coalesced E store
  #pragma unroll
  for (int i = 0; i < 8; i++) {
    int chunk = i * 256 + tid;
    int r  = chunk >> 4;
    int c8 = (chunk & 15) * 8;
    *(half8*)&E[(size_t)(m0 + r) * NATOM + n0 + c8] = *(const half8*)&lds[r * 136 + c8];
  }
  // per-row partial sum (-> atomic lsum) and tile max (-> Tmax, tile-major for coalesced store)
  {
    int r = tid >> 1, h = tid & 1;
    const _Float16* rowp = &lds[r * 136 + h * 64];
    float s = 0.0f, m = 0.0f;
    #pragma unroll
    for (int i = 0; i < 8; i++) {
      half8 v = *(const half8*)&rowp[i * 8];
      #pragma unroll
      for (int j = 0; j < 8; j++) { float f = (float)v[j]; s += f; m = fmaxf(m, f); }
    }
    s += __shfl_xor(s, 1, 64);
    m = fmaxf(m, __shfl_xor(m, 1, 64));
    if (h == 0) {
      atomicAdd(&lsum[m0 + r], s);
      Tmax[(size_t)nt * NTOK + m0 + r] = (_Float16)m;   // nt, NOT blockIdx.x (grid is flat now)
    }
  }
}

// ---------------- kernel 2: sparse argmax scan (1 wave / token) ----------------
__global__ void scan_lite(const _Float16* __restrict__ E,
                          const _Float16* __restrict__ Tmax,
                          const float* __restrict__ x,
                          const float* __restrict__ dict,
                          float* __restrict__ argout) {
  const int t = blockIdx.x;
  const int lane = threadIdx.x;            // 0..63
  float m0 = (float)Tmax[(size_t)lane * NTOK + t];
  float m1 = (float)Tmax[(size_t)(64 + lane) * NTOK + t];
  float mx = fmaxf(m0, m1);
  #pragma unroll
  for (int off = 32; off > 0; off >>= 1) mx = fmaxf(mx, __shfl_xor(mx, off, 64));

  __shared__ int cnt;
  __shared__ int cand[32];
  __shared__ double csc[32];
  if (lane == 0) cnt = 0;
  __syncthreads();

  if (mx > 0.0f) {
    float thr = 0.98f * mx;
    unsigned long long q0 = __ballot(m0 >= thr);
    unsigned long long q1 = __ballot(m1 >= thr);
    while (q0 | q1) {
      int tile;
      if (q0) { tile = __ffsll(q0) - 1; q0 &= q0 - 1; }
      else    { tile = 64 + __ffsll(q1) - 1; q1 &= q1 - 1; }
      const _Float16* ep = E + (size_t)t * NATOM + tile * 128;
      float e0 = (float)ep[lane], e1 = (float)ep[64 + lane];
      if (e0 >= thr) { int p = atomicAdd(&cnt, 1); if (p < 32) cand[p] = tile * 128 + lane; }
      if (e1 >= thr) { int p = atomicAdd(&cnt, 1); if (p < 32) cand[p] = tile * 128 + 64 + lane; }
    }
  }
  __syncthreads();
  int nc = min(cnt, 32);
  const float* xr = x + (size_t)t * DMODEL;
  for (int c = 0; c < nc; c++) {
    const float* dr = dict + (size_t)cand[c] * DMODEL;
    double a = 0.0;
    #pragma unroll
    for (int i = 0; i < 16; i++) {
      int d = lane + i * 64;
      a += (double)xr[d] * (double)dr[d];
    }
    #pragma unroll
    for (int off = 32; off > 0; off >>= 1) a += __shfl_down(a, off, 64);
    if (lane == 0) csc[c] = a;
  }
  __syncthreads();
  if (lane == 0) {
    int best = 0;                          // all-masked -> np.argmax of equal values = 0
    if (nc > 0) {
      double bs = -1e300;
      best = NATOM;
      for (int c = 0; c < nc; c++)
        if (csc[c] > bs || (csc[c] == bs && cand[c] < best)) { bs = csc[c]; best = cand[c]; }
    }
    argout[t] = (float)best;               // harness reads d_out as float32
  }
}

// ---------------- kernel 3: recon = (E @ dT^T) / l ----------------
// M128 x N128, grid 512 (2/CU), same quad-buffered counted-vmcnt loop, K = 16384 (512 tiles).
__launch_bounds__(256, 2)
__global__ void recon_kernel(const _Float16* __restrict__ E,
                             const _Float16* __restrict__ DT,
                             const float* __restrict__ lsum,
                             float* __restrict__ out) {
  __shared__ _Float16 lds[32768];          // 4 bufs x (As 128x32 + Bs 128x32)
  const int tid  = threadIdx.x;
  const int lane = tid & 63;
  const int wave = tid >> 6;
  const int wm = wave >> 1, wn = wave & 1;
  const int swz = (blockIdx.x & 7) * 64 + (blockIdx.x >> 3);
  const int n0 = (swz & 7) * 128;          // d_model tile
  const int m0 = (swz >> 3) * 128;         // token tile

  const int frow = lane & 15;
  const int fkc  = lane >> 4;

  f32x4 acc[4][4] = {};

  stage_ab(E, DT, lds,         lds + 4096,  m0, n0, NATOM, 0,  tid);
  stage_ab(E, DT, lds + 8192,  lds + 12288, m0, n0, NATOM, 32, tid);
  stage_ab(E, DT, lds + 16384, lds + 20480, m0, n0, NATOM, 64, tid);

  for (int t = 0; t < 512; ++t) {
    if (t < 510)       asm volatile("s_waitcnt vmcnt(8)" ::: "memory");
    else if (t == 510) asm volatile("s_waitcnt vmcnt(4)" ::: "memory");
    else               asm volatile("s_waitcnt vmcnt(0)" ::: "memory");
    __builtin_amdgcn_s_barrier();
    __builtin_amdgcn_sched_barrier(0);
    const _Float16* As = lds + (t & 3) * 8192;
    const _Float16* Bs = As + 4096;
    half8 af[4], bf[4];
    #pragma unroll
    for (int i = 0; i < 4; i++) {
      int ar = wm * 64 + i * 16 + frow;
      int br = wn * 64 + i * 16 + frow;
      af[i] = *(const half8*)&As[ar * 32 + ((fkc ^ ((ar >> 1) & 3)) << 3)];
      bf[i] = *(const half8*)&Bs[br * 32 + ((fkc ^ ((br >> 1) & 3)) << 3)];
    }
    if (t + 3 < 512) {
      int b = (t + 3) & 3;
      stage_ab(E, DT, lds + b * 8192, lds + b * 8192 + 4096, m0, n0, NATOM, (t + 3) * 32, tid);
    }
    __builtin_amdgcn_s_setprio(1);
    #pragma unroll
    for (int i = 0; i < 4; i++)
      #pragma unroll
      for (int j = 0; j < 4; j++)
        acc[i][j] = __builtin_amdgcn_mfma_f32_16x16x32_f16(af[i], bf[j], acc[i][j], 0, 0, 0);
    __builtin_amdgcn_s_setprio(0);
    __builtin_amdgcn_sched_barrier(0);
  }

  const int cr = (lane >> 4) * 4;
  const int cc = lane & 15;
  #pragma unroll
  for (int i = 0; i < 4; i++) {
    #pragma unroll
    for (int r = 0; r < 4; r++) {
      int lr = wm * 64 + i * 16 + cr + r;
      float sc = 1.0f / lsum[m0 + lr];
      #pragma unroll
      for (int j = 0; j < 4; j++) {
        int lc = wn * 64 + j * 16 + cc;
        out[(size_t)(m0 + lr) * DMODEL + (n0 + lc)] = acc[i][j][r] * sc;
      }
    }
  }
}

extern "C" void kernel_launch(void* const* d_in, const int* in_sizes, int n_in,
                              void* d_out, int out_size, void* d_ws, size_t ws_size,
                              hipStream_t stream) {
  const float* x    = (const float*)d_in[0];
  const float* dict = (const float*)d_in[1];
  const int*   mask = (const int*)d_in[2];
  float* recon  = (float*)d_out;
  float* argout = recon + (size_t)NTOK * DMODEL;

  // workspace layout (336 MB + 32 KB — proven size)
  char* w = (char*)d_ws;
  _Float16* Xh = (_Float16*)(w);                                 // 16 MB  [8192,1024]
  _Float16* Dh = (_Float16*)(w + (size_t)16  * 1024 * 1024);     // 32 MB  [16384,1024]
  _Float16* DT = (_Float16*)(w + (size_t)48  * 1024 * 1024);     // 32 MB  [1024,16384]
  _Float16* E  = (_Float16*)(w + (size_t)80  * 1024 * 1024);     // 256 MB [8192,16384]
  float*  lsum = (float*)  (w + (size_t)336 * 1024 * 1024);      // 32 KB
  // Tmax (2 MB fp16) borrows the front of d_out's recon region; scan_lite consumes it
  // before recon_kernel overwrites the region (stream-serialized).
  _Float16* Tmax = (_Float16*)d_out;                             // [128][8192]

  cvt_f32_f16<<<dim3(NTOK * DMODEL / 4 / 256), 256, 0, stream>>>(x, Xh, NTOK * DMODEL / 4);
  transpose_dict<<<dim3(NATOM / 64, DMODEL / 64), 256, 0, stream>>>(dict, Dh, DT);
  zero_lsum<<<dim3(NTOK / 256), 256, 0, stream>>>(lsum);
  score_kernel<<<dim3(8192), 256, 0, stream>>>(Xh, Dh, mask, E, lsum, Tmax);
  scan_lite<<<dim3(NTOK), 64, 0, stream>>>(E, Tmax, x, dict, argout);
  recon_kernel<<<dim3(512), 256, 0, stream>>>(E, DT, lsum, recon);
}